// Round 11
// baseline (200.013 us; speedup 1.0000x reference)
//
#include <hip/hip_runtime.h>

#define S_LEN 2048
#define NH 16
#define LOG2E 1.4426950408889634f

typedef _Float16 half8_t __attribute__((ext_vector_type(8)));
typedef _Float16 half4_t __attribute__((ext_vector_type(4)));
typedef _Float16 half2_t __attribute__((ext_vector_type(2)));
typedef float f32x4 __attribute__((ext_vector_type(4)));

__device__ __forceinline__ f32x4 mfma_qk(half8_t a, half8_t b, f32x4 c) {
  return __builtin_amdgcn_mfma_f32_16x16x32_f16(a, b, c, 0, 0, 0);
}
__device__ __forceinline__ void glds16(const void* g, void* l) {
  __builtin_amdgcn_global_load_lds(
      (const __attribute__((address_space(1))) unsigned int*)g,
      (__attribute__((address_space(3))) unsigned int*)l, 16, 0, 0);
}
__device__ __forceinline__ float fexp2(float x) {
#if __has_builtin(__builtin_amdgcn_exp2f)
  return __builtin_amdgcn_exp2f(x);   // raw v_exp_f32, 1 instr
#else
  return exp2f(x);
#endif
}

// ---------------- fused prep: fp32->fp16 cvts + both weight transposes ----------
__global__ __launch_bounds__(256) void prep_kernel(const float* __restrict__ x,
                                                   const float* __restrict__ pos_embed,
                                                   const float* __restrict__ W_pos,
                                                   const float* __restrict__ W_tok,
                                                   _Float16* __restrict__ x_f,
                                                   _Float16* __restrict__ pos_f,
                                                   _Float16* __restrict__ wt_pos,
                                                   _Float16* __restrict__ wt_tok) {
  __shared__ float tile[64][65];
  const int bid = blockIdx.x, tid = threadIdx.x;
  if (bid < 6144) {
    // elementwise cvt: 1,572,864 float4 total (pos_embed first 524288, then x)
    int id = bid * 256 + tid;
    const float* src; _Float16* dst;
    if (id < 524288) { src = pos_embed; dst = pos_f; }
    else { id -= 524288; src = x; dst = x_f; }
    float4 f = ((const float4*)src)[id];
    half4_t o = {(_Float16)f.x, (_Float16)f.y, (_Float16)f.z, (_Float16)f.w};
    ((half4_t*)dst)[id] = o;
    return;
  }
  // weight transpose fp32 [K,N] -> fp16 [N,K], K=1024
  const float* W; _Float16* Wt; int N, nx, ky;
  if (bid < 6656) { W = W_pos; Wt = wt_pos; N = 2048; int t = bid - 6144; nx = t & 31; ky = t >> 5; }
  else            { W = W_tok; Wt = wt_tok; N = 3072; int t = bid - 6656; nx = t % 48; ky = t / 48; }
  int k0 = ky * 64, n0 = nx * 64;
  int tx = tid & 63, ty = tid >> 6;
  for (int j = 0; j < 16; ++j) {
    int k = ty * 16 + j;
    tile[k][tx] = W[(size_t)(k0 + k) * N + n0 + tx];
  }
  __syncthreads();
  for (int j = 0; j < 16; ++j) {
    int n = ty * 16 + j;
    Wt[(size_t)(n0 + n) * 1024 + k0 + tx] = (_Float16)tile[tx][n];
  }
}

// ---------------- merged fp16 GEMM (pos + tok), fragment-layout epilogues ------
// blocks [0,256):   pos gemm  2048x2048, A=pos_f, Bt=wt_pos, kg=KGP, qr=QRp
// blocks [256,1024): tok gemm 4096x3072, A=x_f,  Bt=wt_tok, kg=KG,  qr=QRt, vg=VG
// 2-phase double-buffered K-loop (R7-verified). V epilogue writes the
// PAIR-INTERLEAVED layout (R8-verified): feeds flash's K=32 PV fusion.
__global__ __launch_bounds__(256) void gemm_all_kernel(const _Float16* __restrict__ pos_f,
                                                       const _Float16* __restrict__ wt_pos,
                                                       const _Float16* __restrict__ x_f,
                                                       const _Float16* __restrict__ wt_tok,
                                                       _Float16* __restrict__ KGP,
                                                       _Float16* __restrict__ QRp,
                                                       _Float16* __restrict__ KG,
                                                       _Float16* __restrict__ QRt,
                                                       _Float16* __restrict__ VG,
                                                       float qscale) {
  __shared__ _Float16 SMem[16384];       // 32 KB: 2x (Ald|Bld) double-buffer
  _Float16* buf0 = SMem;                 // [0,4096)=A  [4096,8192)=B
  _Float16* buf1 = SMem + 8192;

  const int bid = blockIdx.x, tid = threadIdx.x;
  const _Float16 *A, *Bt; _Float16 *kg, *qr, *vg;
  int m0, n0;
  if (bid < 256) {
    A = pos_f; Bt = wt_pos; kg = KGP; qr = QRp; vg = nullptr;
    m0 = (bid >> 4) * 128; n0 = (bid & 15) * 128;
  } else {
    int t = bid - 256;
    A = x_f; Bt = wt_tok; kg = KG; qr = QRt; vg = VG;
    m0 = (t / 24) * 128; n0 = (t % 24) * 128;
  }
  const int K = 1024;

  const int wave = tid >> 6, lane = tid & 63;
  const int quad = lane >> 4, l16 = lane & 15;
  const int wm = (wave >> 1) * 64, wn = (wave & 1) * 64;

  f32x4 acc[4][4] = {};
  const int flat0 = tid, flat1 = tid + 256;
  const int r0 = flat0 >> 2, c0 = flat0 & 3;
  const int r1 = flat1 >> 2, c1 = flat1 & 3;

  auto stage = [&](int ko, _Float16* buf) {
    glds16(A + (size_t)(m0 + r0) * K + ko + c0 * 8, &buf[flat0 * 8]);
    glds16(Bt + (size_t)(n0 + r0) * K + ko + c0 * 8, &buf[4096 + flat0 * 8]);
    glds16(A + (size_t)(m0 + r1) * K + ko + c1 * 8, &buf[flat1 * 8]);
    glds16(Bt + (size_t)(n0 + r1) * K + ko + c1 * 8, &buf[4096 + flat1 * 8]);
  };
  auto kstep = [&](const _Float16* buf) {
    half8_t af[4], bfv[4];
    #pragma unroll
    for (int t = 0; t < 4; ++t) {
      af[t]  = *(const half8_t*)&buf[(wm + t * 16 + l16) * 32 + quad * 8];
      bfv[t] = *(const half8_t*)&buf[4096 + (wn + t * 16 + l16) * 32 + quad * 8];
    }
    #pragma unroll
    for (int mi = 0; mi < 4; ++mi)
      #pragma unroll
      for (int ni = 0; ni < 4; ++ni)
        acc[mi][ni] = mfma_qk(af[mi], bfv[ni], acc[mi][ni]);
  };

  stage(0, buf0);
  __syncthreads();
  #pragma unroll 1
  for (int ko = 0; ko < K; ko += 64) {
    stage(ko + 32, buf1);                 // next tile issues before compute
    kstep(buf0);
    __syncthreads();                      // readers done + buf1 loads landed
    if (ko + 64 < K) stage(ko + 64, buf0);
    kstep(buf1);
    __syncthreads();
  }
  // last barrier above also protects SMem before epilogue scratch reuse

  const int n_base = n0 + wn, m_base = m0 + wm;   // both 64-aligned
  const int bb = m_base >> 11;
  const int tile16 = (m_base & 2047) >> 6;

  if (n_base >= 2048) {
    // V region (tok only), pair-interleaved:
    // idx = ((mi>>1)*4 + ni)*512 + quad*128 + l16*8 + (mi&1)*4
    int hh = (n_base >> 6) & 15;
    _Float16* dstb = vg + (size_t)((bb * 16 + hh) * 32 + tile16) * 4096;
    #pragma unroll
    for (int mi = 0; mi < 4; ++mi)
      #pragma unroll
      for (int ni = 0; ni < 4; ++ni) {
        union { ushort4 u; _Float16 h[4]; } pk;
        #pragma unroll
        for (int r = 0; r < 4; ++r) pk.h[r] = (_Float16)acc[mi][ni][r];
        *(ushort4*)(dstb + ((mi >> 1) * 4 + ni) * 512 + quad * 128 + l16 * 8 +
                    (mi & 1) * 4) = pk.u;
      }
  } else if (n_base >= 1024) {
    // Q region: row-major, scaled
    #pragma unroll
    for (int mi = 0; mi < 4; ++mi)
      #pragma unroll
      for (int ni = 0; ni < 4; ++ni)
        #pragma unroll
        for (int r = 0; r < 4; ++r) {
          int m = m_base + mi * 16 + quad * 4 + r;
          int col = n_base - 1024 + ni * 16 + l16;
          qr[(size_t)m * 1024 + col] = (_Float16)(acc[mi][ni][r] * qscale);
        }
  } else {
    // K region: in-lane dim-transpose, 2 rounds of 32 keys through 4 KB/wave scratch
    int hh = n_base >> 6;
    int bhk = vg ? (bb * 16 + hh) : hh;
    _Float16* dstb = kg + (size_t)(bhk * 32 + tile16) * 4096;
    _Float16* Tr = SMem + wave * 2048;       // per-wave private 4 KB
    #pragma unroll
    for (int p = 0; p < 2; ++p) {
      #pragma unroll
      for (int mi2 = 0; mi2 < 2; ++mi2) {
        int mi = p * 2 + mi2;
        #pragma unroll
        for (int ni = 0; ni < 4; ++ni)
          #pragma unroll
          for (int r = 0; r < 4; ++r) {
            int keyp = mi2 * 16 + quad * 4 + r;            // 0..31
            int dim = ni * 16 + l16;
            int col = (((dim >> 3) ^ (keyp & 7)) << 3) | (dim & 7);
            Tr[keyp * 64 + col] = (_Float16)acc[mi][ni][r];
          }
      }
      #pragma unroll
      for (int j = 0; j < 4; ++j) {
        int wkp = j >> 1, kfl = j & 1;
        int wk = p * 2 + wkp;
        half8_t v = *(const half8_t*)&Tr[(wkp * 16 + l16) * 64 +
                                         (((kfl * 4 + quad) ^ (l16 & 7)) << 3)];
        *(half8_t*)(dstb + wk * 1024 + kfl * 512 + quad * 128 + l16 * 8) = v;
      }
    }
  }
}

// ---------------- fused flash attention v13: 2 blocks/CU cross-block TLP ----------
// 128 q-rows/block, grid 512, 512 threads = 8 waves = 2 kw x 4 qw, 32 q-rows/
// wave (qt=2). K/V LDS-dbuf per tile (24KB x2); independent co-resident blocks
// (NOT barrier-synced) give 4 waves/SIMD that drift anti-phase -- block A's
// MFMA fills block B's exp/wait bubbles (m114 co-scheduling). Key-fragments
// processed serially within a tile to keep peak regs <= 128 for 2-block
// residency (launch_bounds(512,4)). L2 stream 2x (393 MB ~ 11 us, absorbed).
// Guards: WRITE_SIZE 16.4 MB (spill), OccupancyPercent ~2x (co-residency).
__global__ __launch_bounds__(512, 4) void flash_kernel(const _Float16* __restrict__ QRt,
                                                       const _Float16* __restrict__ QRp,
                                                       const _Float16* __restrict__ KG,
                                                       const _Float16* __restrict__ KGP,
                                                       const _Float16* __restrict__ VG,
                                                       const float* __restrict__ bias_table,
                                                       float* __restrict__ out) {
  __shared__ __align__(16) unsigned char SM[75776];
  _Float16* SK = (_Float16*)SM;             // [2][12288] halfs: Ktok|Kpos|V dbuf (48KB)
  float* ored  = (float*)SM;                // [128][36] fp32 overlay after loop (72KB)
  float* biasl = (float*)(SM + 73728);      // 384 floats
  float* lred  = (float*)(SM + 75264);      // 128 floats

  const int tid = threadIdx.x;
  const int wave = tid >> 6, lane = tid & 63;
  const int quad = lane >> 4, l16 = lane & 15;
  const int qw = wave & 3, kw = wave >> 2;
  const int lbid = blockIdx.x;
  const int q0 = ((lbid >> 3) & 15) * 128;       // 16 q-blocks per bh
  const int bh = (lbid & 7) + 8 * (lbid >> 7);   // bh's q-blocks share one XCD
  const int b = bh >> 4, h = bh & 15;

  if (tid < 384) {
    int i = tid;
    int delta = i - 192;
    int n = -delta;
    int ret = (n < 0) ? 16 : 0;
    int na = (n < 0) ? -n : n;
    int bkt;
    if (na < 8) bkt = na;
    else {
      int s2 = (na >= 12) + (na >= 16) + (na >= 23) + (na >= 32) +
               (na >= 46) + (na >= 64) + (na >= 91) + (na >= 128);
      bkt = 8 + s2; if (bkt > 15) bkt = 15;
    }
    bkt += ret;
    biasl[i] = bias_table[(size_t)(2048 + bkt) * NH + h] * LOG2E;
  }
  const float b_lo = bias_table[(2048 + 15) * NH + h] * LOG2E;
  const float b_hi = bias_table[(2048 + 31) * NH + h] * LOG2E;

  // Q fragments (pre-scaled in gemm epilogue); wave's rows = qbase+qt*16+l16
  const int qbase = q0 + qw * 32;
  half8_t qf[4][2];
  {
    const _Float16* tq = QRt + (size_t)(b * S_LEN + qbase + l16) * 1024 + h * 64 + quad * 8;
    const _Float16* pq = QRp + (size_t)(qbase + l16) * 1024 + h * 64 + quad * 8;
    #pragma unroll
    for (int qt = 0; qt < 2; ++qt)
      #pragma unroll
      for (int kf = 0; kf < 2; ++kf) {
        qf[kf][qt]     = *(const half8_t*)(tq + (size_t)qt * 16 * 1024 + kf * 32);
        qf[kf + 2][qt] = *(const half8_t*)(pq + (size_t)qt * 16 * 1024 + kf * 32);
      }
  }

  const _Float16* kgp = KG  + (size_t)bh * 131072;
  const _Float16* kpp = KGP + (size_t)h  * 131072;
  const _Float16* vgp = VG  + (size_t)bh * 131072;

  auto stage = [&](int t, int par) {
    _Float16* dst = SK + par * 12288;
    glds16(kgp + (size_t)t * 4096 + tid * 8, dst + tid * 8);
    glds16(kpp + (size_t)t * 4096 + tid * 8, dst + 4096 + tid * 8);
    glds16(vgp + (size_t)t * 4096 + tid * 8, dst + 8192 + tid * 8);
  };

  f32x4 oa[4][2] = {};
  float lpart[2] = {0.f, 0.f};
  union VP8 { half8_t h8; struct { half4_t lo, hi; } p; };

  stage(0, 0);
  __syncthreads();   // also covers biasl

  #pragma unroll 1
  for (int t = 0; t < 32; ++t) {
    if (t != 31) stage(t + 1, (t + 1) & 1);
    const _Float16* Bse = SK + (t & 1) * 12288;
    const int dk = t * 64 - qbase;          // 32-granular
    const int f0 = kw * 2;
    const bool splat = (dk < -160 || dk > 128);
    const float csplat = (dk < 0) ? b_lo : b_hi;

    VP8 pc[2];
    // ---- key-fragment 0 (serial to bound peak regs) ----
    {
      half8_t kf_[4];
      kf_[0] = *(const half8_t*)&Bse[f0 * 1024 + lane * 8];
      kf_[1] = *(const half8_t*)&Bse[f0 * 1024 + 512 + lane * 8];
      kf_[2] = *(const half8_t*)&Bse[4096 + f0 * 1024 + lane * 8];
      kf_[3] = *(const half8_t*)&Bse[4096 + f0 * 1024 + 512 + lane * 8];
      f32x4 s[2];
      if (splat) {
        #pragma unroll
        for (int qt = 0; qt < 2; ++qt) s[qt] = {csplat, csplat, csplat, csplat};
      } else {
        #pragma unroll
        for (int qt = 0; qt < 2; ++qt) {
          int dbase = dk + f0 * 16 + quad * 4 - qt * 16 - l16 + 192;
          #pragma unroll
          for (int r = 0; r < 4; ++r) s[qt][r] = biasl[dbase + r];
        }
      }
      __builtin_amdgcn_s_setprio(1);
      #pragma unroll
      for (int qt = 0; qt < 2; ++qt)
        #pragma unroll
        for (int kf = 0; kf < 4; ++kf)
          s[qt] = mfma_qk(kf_[kf], qf[kf][qt], s[qt]);
      __builtin_amdgcn_s_setprio(0);
      #pragma unroll
      for (int qt = 0; qt < 2; ++qt) {
        float p0 = fexp2(s[qt][0]), p1 = fexp2(s[qt][1]);
        float p2 = fexp2(s[qt][2]), p3 = fexp2(s[qt][3]);
        lpart[qt] += (p0 + p1) + (p2 + p3);
        union { half2_t h2[2]; half4_t h4; } u;
        u.h2[0] = __builtin_bit_cast(half2_t, __builtin_amdgcn_cvt_pkrtz(p0, p1));
        u.h2[1] = __builtin_bit_cast(half2_t, __builtin_amdgcn_cvt_pkrtz(p2, p3));
        pc[qt].p.lo = u.h4;
      }
    }
    // ---- key-fragment 1 ----
    {
      half8_t kf_[4];
      kf_[0] = *(const half8_t*)&Bse[(f0 + 1) * 1024 + lane * 8];
      kf_[1] = *(const half8_t*)&Bse[(f0 + 1) * 1024 + 512 + lane * 8];
      kf_[2] = *(const half8_t*)&Bse[4096 + (f0 + 1) * 1024 + lane * 8];
      kf_[3] = *(const half8_t*)&Bse[4096 + (f0 + 1) * 1024 + 512 + lane * 8];
      f32x4 s[2];
      if (splat) {
        #pragma unroll
        for (int qt = 0; qt < 2; ++qt) s[qt] = {csplat, csplat, csplat, csplat};
      } else {
        #pragma unroll
        for (int qt = 0; qt < 2; ++qt) {
          int dbase = dk + f0 * 16 + quad * 4 - qt * 16 - l16 + 192;
          #pragma unroll
          for (int r = 0; r < 4; ++r) s[qt][r] = biasl[dbase + 16 + r];
        }
      }
      __builtin_amdgcn_s_setprio(1);
      #pragma unroll
      for (int qt = 0; qt < 2; ++qt)
        #pragma unroll
        for (int kf = 0; kf < 4; ++kf)
          s[qt] = mfma_qk(kf_[kf], qf[kf][qt], s[qt]);
      __builtin_amdgcn_s_setprio(0);
      #pragma unroll
      for (int qt = 0; qt < 2; ++qt) {
        float p0 = fexp2(s[qt][0]), p1 = fexp2(s[qt][1]);
        float p2 = fexp2(s[qt][2]), p3 = fexp2(s[qt][3]);
        lpart[qt] += (p0 + p1) + (p2 + p3);
        union { half2_t h2[2]; half4_t h4; } u;
        u.h2[0] = __builtin_bit_cast(half2_t, __builtin_amdgcn_cvt_pkrtz(p0, p1));
        u.h2[1] = __builtin_bit_cast(half2_t, __builtin_amdgcn_cvt_pkrtz(p2, p3));
        pc[qt].p.hi = u.h4;
      }
    }
    // ---- PV (V loaded after QK to bound peak regs) ----
    __builtin_amdgcn_s_setprio(1);
    #pragma unroll
    for (int d = 0; d < 4; ++d) {
      half8_t vc = *(const half8_t*)&Bse[8192 + (kw * 4 + d) * 512 + lane * 8];
      #pragma unroll
      for (int qt = 0; qt < 2; ++qt)
        oa[d][qt] = mfma_qk(vc, pc[qt].h8, oa[d][qt]);
    }
    __builtin_amdgcn_s_setprio(0);
    __syncthreads();   // staged t+1 landed; buffer t free for t+2
  }

  // ---- cross-half combine (kw=1 -> LDS, kw=0 adds + stores), 2 d-rounds ----
  #pragma unroll
  for (int qt = 0; qt < 2; ++qt) {
    lpart[qt] += __shfl_xor(lpart[qt], 16, 64);
    lpart[qt] += __shfl_xor(lpart[qt], 32, 64);
  }
  if (kw == 1) {
    if (quad == 0) {
      #pragma unroll
      for (int qt = 0; qt < 2; ++qt) lred[qw * 32 + qt * 16 + l16] = lpart[qt];
    }
    #pragma unroll
    for (int d = 0; d < 2; ++d)
      #pragma unroll
      for (int qt = 0; qt < 2; ++qt)
        *(f32x4*)&ored[(qw * 32 + qt * 16 + l16) * 36 + d * 16 + quad * 4] = oa[d][qt];
  }
  __syncthreads();
  float inv[2];
  if (kw == 0) {
    #pragma unroll
    for (int qt = 0; qt < 2; ++qt)
      inv[qt] = 1.f / (lpart[qt] + lred[qw * 32 + qt * 16 + l16]);
    #pragma unroll
    for (int d = 0; d < 2; ++d)
      #pragma unroll
      for (int qt = 0; qt < 2; ++qt) {
        f32x4 p = *(const f32x4*)&ored[(qw * 32 + qt * 16 + l16) * 36 + d * 16 + quad * 4];
        f32x4 sum = oa[d][qt] + p;
        sum[0] *= inv[qt]; sum[1] *= inv[qt]; sum[2] *= inv[qt]; sum[3] *= inv[qt];
        *(f32x4*)(out + (size_t)(b * S_LEN + qbase + qt * 16 + l16) * 1024 +
                  h * 64 + d * 16 + quad * 4) = sum;
      }
  }
  __syncthreads();
  if (kw == 1) {
    #pragma unroll
    for (int d = 2; d < 4; ++d)
      #pragma unroll
      for (int qt = 0; qt < 2; ++qt)
        *(f32x4*)&ored[(qw * 32 + qt * 16 + l16) * 36 + (d - 2) * 16 + quad * 4] = oa[d][qt];
  }
  __syncthreads();
  if (kw == 0) {
    #pragma unroll
    for (int d = 2; d < 4; ++d)
      #pragma unroll
      for (int qt = 0; qt < 2; ++qt) {
        f32x4 p = *(const f32x4*)&ored[(qw * 32 + qt * 16 + l16) * 36 + (d - 2) * 16 + quad * 4];
        f32x4 sum = oa[d][qt] + p;
        sum[0] *= inv[qt]; sum[1] *= inv[qt]; sum[2] *= inv[qt]; sum[3] *= inv[qt];
        *(f32x4*)(out + (size_t)(b * S_LEN + qbase + qt * 16 + l16) * 1024 +
                  h * 64 + (d - 2) * 16 + quad * 4 + 32) = sum;
      }
  }
}

extern "C" void kernel_launch(void* const* d_in, const int* in_sizes, int n_in,
                              void* d_out, int out_size, void* d_ws, size_t ws_size,
                              hipStream_t stream) {
  (void)in_sizes; (void)n_in; (void)out_size; (void)ws_size;
  const float* x          = (const float*)d_in[0];
  const float* pos_embed  = (const float*)d_in[1];
  const float* W_pos_kq   = (const float*)d_in[2];
  const float* W_tok_kqv  = (const float*)d_in[3];
  const float* bias_table = (const float*)d_in[4];
  float* out = (float*)d_out;

  _Float16* ws = (_Float16*)d_ws;
  _Float16* pos_f  = ws;                     // 2,097,152
  _Float16* wt_pos = ws + 2097152;           // 2,097,152
  _Float16* x_f    = ws + 4194304;           // 4,194,304
  _Float16* wt_tok = ws + 8388608;           // 3,145,728
  _Float16* KG     = ws + 11534336;          // 4,194,304
  _Float16* KGP    = ws + 15728640;          // 2,097,152
  _Float16* VG     = ws + 17825792;          // 4,194,304
  _Float16* QRt    = ws + 22020096;          // 4,194,304
  _Float16* QRp    = ws + 26214400;          // 2,097,152
  // total 28,311,552 halfs = 56.6 MB

  const float QSCALE = 0.08838834764831845f * LOG2E;  // 1/sqrt(2*64) * log2e

  prep_kernel<<<7424, 256, 0, stream>>>(x, pos_embed, W_pos_kq, W_tok_kqv,
                                        x_f, pos_f, wt_pos, wt_tok);
  gemm_all_kernel<<<1024, 256, 0, stream>>>(pos_f, wt_pos, x_f, wt_tok,
                                            KGP, QRp, KG, QRt, VG, QSCALE);
  flash_kernel<<<512, 512, 0, stream>>>(QRt, QRp, KG, KGP, VG, bias_table, out);
}

// Round 12
// 186.049 us; speedup vs baseline: 1.0751x; 1.0751x over previous
//
#include <hip/hip_runtime.h>

#define S_LEN 2048
#define NH 16
#define LOG2E 1.4426950408889634f

typedef _Float16 half8_t __attribute__((ext_vector_type(8)));
typedef _Float16 half4_t __attribute__((ext_vector_type(4)));
typedef _Float16 half2_t __attribute__((ext_vector_type(2)));
typedef float f32x4 __attribute__((ext_vector_type(4)));

__device__ __forceinline__ f32x4 mfma_qk(half8_t a, half8_t b, f32x4 c) {
  return __builtin_amdgcn_mfma_f32_16x16x32_f16(a, b, c, 0, 0, 0);
}
__device__ __forceinline__ void glds16(const void* g, void* l) {
  __builtin_amdgcn_global_load_lds(
      (const __attribute__((address_space(1))) unsigned int*)g,
      (__attribute__((address_space(3))) unsigned int*)l, 16, 0, 0);
}
__device__ __forceinline__ float fexp2(float x) {
#if __has_builtin(__builtin_amdgcn_exp2f)
  return __builtin_amdgcn_exp2f(x);   // raw v_exp_f32, 1 instr
#else
  return exp2f(x);
#endif
}

// ---------------- fused prep: fp32->fp16 cvts + both weight transposes ----------
__global__ __launch_bounds__(256) void prep_kernel(const float* __restrict__ x,
                                                   const float* __restrict__ pos_embed,
                                                   const float* __restrict__ W_pos,
                                                   const float* __restrict__ W_tok,
                                                   _Float16* __restrict__ x_f,
                                                   _Float16* __restrict__ pos_f,
                                                   _Float16* __restrict__ wt_pos,
                                                   _Float16* __restrict__ wt_tok) {
  __shared__ float tile[64][65];
  const int bid = blockIdx.x, tid = threadIdx.x;
  if (bid < 6144) {
    // elementwise cvt: 1,572,864 float4 total (pos_embed first 524288, then x)
    int id = bid * 256 + tid;
    const float* src; _Float16* dst;
    if (id < 524288) { src = pos_embed; dst = pos_f; }
    else { id -= 524288; src = x; dst = x_f; }
    float4 f = ((const float4*)src)[id];
    half4_t o = {(_Float16)f.x, (_Float16)f.y, (_Float16)f.z, (_Float16)f.w};
    ((half4_t*)dst)[id] = o;
    return;
  }
  // weight transpose fp32 [K,N] -> fp16 [N,K], K=1024
  const float* W; _Float16* Wt; int N, nx, ky;
  if (bid < 6656) { W = W_pos; Wt = wt_pos; N = 2048; int t = bid - 6144; nx = t & 31; ky = t >> 5; }
  else            { W = W_tok; Wt = wt_tok; N = 3072; int t = bid - 6656; nx = t % 48; ky = t / 48; }
  int k0 = ky * 64, n0 = nx * 64;
  int tx = tid & 63, ty = tid >> 6;
  for (int j = 0; j < 16; ++j) {
    int k = ty * 16 + j;
    tile[k][tx] = W[(size_t)(k0 + k) * N + n0 + tx];
  }
  __syncthreads();
  for (int j = 0; j < 16; ++j) {
    int n = ty * 16 + j;
    Wt[(size_t)(n0 + n) * 1024 + k0 + tx] = (_Float16)tile[tx][n];
  }
}

// ---------------- merged fp16 GEMM (pos + tok), fragment-layout epilogues ------
// NEW geometry: BM=256 x BN=128, 512 blocks x 512 threads (8 waves = 4M x 2N),
// each wave still owns a 64x64 output tile -> all epilogues preserved verbatim
// (they depend only on 64-aligned m_base/n_base). Staged bytes/FLOP -25%,
// epilogue instances halved. 2-phase dbuf loop (R7-verified) unchanged.
// blocks [0,128):  pos gemm 2048x2048
// blocks [128,512): tok gemm 4096x3072
__global__ __launch_bounds__(512) void gemm_all_kernel(const _Float16* __restrict__ pos_f,
                                                       const _Float16* __restrict__ wt_pos,
                                                       const _Float16* __restrict__ x_f,
                                                       const _Float16* __restrict__ wt_tok,
                                                       _Float16* __restrict__ KGP,
                                                       _Float16* __restrict__ QRp,
                                                       _Float16* __restrict__ KG,
                                                       _Float16* __restrict__ QRt,
                                                       _Float16* __restrict__ VG,
                                                       float qscale) {
  __shared__ _Float16 SMem[24576];       // 48 KB: 2x (A 16KB | B 8KB) double-buffer
  _Float16* buf0 = SMem;                 // [0,8192)=A  [8192,12288)=B
  _Float16* buf1 = SMem + 12288;

  const int bid = blockIdx.x, tid = threadIdx.x;
  const _Float16 *A, *Bt; _Float16 *kg, *qr, *vg;
  int m0, n0;
  if (bid < 128) {
    A = pos_f; Bt = wt_pos; kg = KGP; qr = QRp; vg = nullptr;
    m0 = (bid >> 4) * 256; n0 = (bid & 15) * 128;
  } else {
    int t = bid - 128;
    A = x_f; Bt = wt_tok; kg = KG; qr = QRt; vg = VG;
    m0 = (t / 24) * 256; n0 = (t % 24) * 128;
  }
  const int K = 1024;

  const int wave = tid >> 6, lane = tid & 63;
  const int quad = lane >> 4, l16 = lane & 15;
  const int wm = (wave >> 1) * 64, wn = (wave & 1) * 64;

  f32x4 acc[4][4] = {};
  const int fa0 = tid, fa1 = tid + 512;            // A: 1024 x 16B chunks
  const int ra0 = fa0 >> 2, ca0 = fa0 & 3;
  const int ra1 = fa1 >> 2, ca1 = fa1 & 3;
  const int rb = tid >> 2, cb = tid & 3;           // B: 512 x 16B chunks

  auto stage = [&](int ko, _Float16* buf) {
    glds16(A + (size_t)(m0 + ra0) * K + ko + ca0 * 8, &buf[fa0 * 8]);
    glds16(A + (size_t)(m0 + ra1) * K + ko + ca1 * 8, &buf[fa1 * 8]);
    glds16(Bt + (size_t)(n0 + rb) * K + ko + cb * 8, &buf[8192 + tid * 8]);
  };
  auto kstep = [&](const _Float16* buf) {
    half8_t af[4], bfv[4];
    #pragma unroll
    for (int t = 0; t < 4; ++t) {
      af[t]  = *(const half8_t*)&buf[(wm + t * 16 + l16) * 32 + quad * 8];
      bfv[t] = *(const half8_t*)&buf[8192 + (wn + t * 16 + l16) * 32 + quad * 8];
    }
    #pragma unroll
    for (int mi = 0; mi < 4; ++mi)
      #pragma unroll
      for (int ni = 0; ni < 4; ++ni)
        acc[mi][ni] = mfma_qk(af[mi], bfv[ni], acc[mi][ni]);
  };

  stage(0, buf0);
  __syncthreads();
  #pragma unroll 1
  for (int ko = 0; ko < K; ko += 64) {
    stage(ko + 32, buf1);                 // next tile issues before compute
    kstep(buf0);
    __syncthreads();                      // readers done + buf1 loads landed
    if (ko + 64 < K) stage(ko + 64, buf0);
    kstep(buf1);
    __syncthreads();
  }
  // last barrier above also protects SMem before epilogue scratch reuse

  const int n_base = n0 + wn, m_base = m0 + wm;   // both 64-aligned
  const int bb = m_base >> 11;
  const int tile16 = (m_base & 2047) >> 6;

  if (n_base >= 2048) {
    // V region (tok only), pair-interleaved:
    // idx = ((mi>>1)*4 + ni)*512 + quad*128 + l16*8 + (mi&1)*4
    int hh = (n_base >> 6) & 15;
    _Float16* dstb = vg + (size_t)((bb * 16 + hh) * 32 + tile16) * 4096;
    #pragma unroll
    for (int mi = 0; mi < 4; ++mi)
      #pragma unroll
      for (int ni = 0; ni < 4; ++ni) {
        union { ushort4 u; _Float16 h[4]; } pk;
        #pragma unroll
        for (int r = 0; r < 4; ++r) pk.h[r] = (_Float16)acc[mi][ni][r];
        *(ushort4*)(dstb + ((mi >> 1) * 4 + ni) * 512 + quad * 128 + l16 * 8 +
                    (mi & 1) * 4) = pk.u;
      }
  } else if (n_base >= 1024) {
    // Q region: row-major, scaled
    #pragma unroll
    for (int mi = 0; mi < 4; ++mi)
      #pragma unroll
      for (int ni = 0; ni < 4; ++ni)
        #pragma unroll
        for (int r = 0; r < 4; ++r) {
          int m = m_base + mi * 16 + quad * 4 + r;
          int col = n_base - 1024 + ni * 16 + l16;
          qr[(size_t)m * 1024 + col] = (_Float16)(acc[mi][ni][r] * qscale);
        }
  } else {
    // K region: in-lane dim-transpose, 2 rounds of 32 keys through 4 KB/wave scratch
    int hh = n_base >> 6;
    int bhk = vg ? (bb * 16 + hh) : hh;
    _Float16* dstb = kg + (size_t)(bhk * 32 + tile16) * 4096;
    _Float16* Tr = SMem + wave * 2048;       // per-wave private 4 KB (8 waves = 32KB)
    #pragma unroll
    for (int p = 0; p < 2; ++p) {
      #pragma unroll
      for (int mi2 = 0; mi2 < 2; ++mi2) {
        int mi = p * 2 + mi2;
        #pragma unroll
        for (int ni = 0; ni < 4; ++ni)
          #pragma unroll
          for (int r = 0; r < 4; ++r) {
            int keyp = mi2 * 16 + quad * 4 + r;            // 0..31
            int dim = ni * 16 + l16;
            int col = (((dim >> 3) ^ (keyp & 7)) << 3) | (dim & 7);
            Tr[keyp * 64 + col] = (_Float16)acc[mi][ni][r];
          }
      }
      #pragma unroll
      for (int j = 0; j < 4; ++j) {
        int wkp = j >> 1, kfl = j & 1;
        int wk = p * 2 + wkp;
        half8_t v = *(const half8_t*)&Tr[(wkp * 16 + l16) * 64 +
                                         (((kfl * 4 + quad) ^ (l16 & 7)) << 3)];
        *(half8_t*)(dstb + wk * 1024 + kfl * 512 + quad * 128 + l16 * 8) = v;
      }
    }
  }
}

// ---------------- fused flash attention v12 (R10-verified BEST: 56.9 us) --------
// FROZEN. 256 q-rows/block, grid 256, 8 waves (2kw x 4qw), pair-deep LDS
// staging (4 tile-buffers, 1 barrier per 2 tiles), batched tile body, K=32 PV
// fusion. R11 proved cross-block TLP does NOT help (MfmaUtil pinned ~35%
// across 4 structures -- per-wave QK->exp->PV chain is the limiter).
__global__ __launch_bounds__(512, 1) void flash_kernel(const _Float16* __restrict__ QRt,
                                                       const _Float16* __restrict__ QRp,
                                                       const _Float16* __restrict__ KG,
                                                       const _Float16* __restrict__ KGP,
                                                       const _Float16* __restrict__ VG,
                                                       const float* __restrict__ bias_table,
                                                       float* __restrict__ out) {
  __shared__ __align__(16) unsigned char SM[100864];
  _Float16* SK = (_Float16*)SM;             // [4][12288] halfs: Ktok|Kpos|V, 4 tile-buffers
  float* ored  = (float*)SM;                // [4][64][36] fp32, overlay after loop
  float* biasl = (float*)(SM + 98304);      // 384 floats
  float* lred  = (float*)(SM + 99840);      // [4][64] floats

  const int tid = threadIdx.x;
  const int wave = tid >> 6, lane = tid & 63;
  const int quad = lane >> 4, l16 = lane & 15;
  const int qw = wave & 3, kw = wave >> 2;
  const int lbid = blockIdx.x;
  const int q0 = ((lbid >> 3) & 7) * 256;        // 8 q-blocks per bh
  const int bh = (lbid & 7) + 8 * (lbid >> 6);   // bh's q-blocks share one XCD
  const int b = bh >> 4, h = bh & 15;

  if (tid < 384) {
    int i = tid;
    int delta = i - 192;
    int n = -delta;
    int ret = (n < 0) ? 16 : 0;
    int na = (n < 0) ? -n : n;
    int bkt;
    if (na < 8) bkt = na;
    else {
      int s2 = (na >= 12) + (na >= 16) + (na >= 23) + (na >= 32) +
               (na >= 46) + (na >= 64) + (na >= 91) + (na >= 128);
      bkt = 8 + s2; if (bkt > 15) bkt = 15;
    }
    bkt += ret;
    biasl[i] = bias_table[(size_t)(2048 + bkt) * NH + h] * LOG2E;
  }
  const float b_lo = bias_table[(2048 + 15) * NH + h] * LOG2E;
  const float b_hi = bias_table[(2048 + 31) * NH + h] * LOG2E;

  // Q fragments (pre-scaled in gemm epilogue); wave's rows = q0+qw*64+qt*16+l16
  const int qbase = q0 + qw * 64;
  half8_t qf[4][4];
  {
    const _Float16* tq = QRt + (size_t)(b * S_LEN + qbase + l16) * 1024 + h * 64 + quad * 8;
    const _Float16* pq = QRp + (size_t)(qbase + l16) * 1024 + h * 64 + quad * 8;
    #pragma unroll
    for (int qt = 0; qt < 4; ++qt)
      #pragma unroll
      for (int kf = 0; kf < 2; ++kf) {
        qf[kf][qt]     = *(const half8_t*)(tq + (size_t)qt * 16 * 1024 + kf * 32);
        qf[kf + 2][qt] = *(const half8_t*)(pq + (size_t)qt * 16 * 1024 + kf * 32);
      }
  }

  const _Float16* kgp = KG  + (size_t)bh * 131072;
  const _Float16* kpp = KGP + (size_t)h  * 131072;
  const _Float16* vgp = VG  + (size_t)bh * 131072;

  auto stage = [&](int t, int buf) {
    _Float16* dst = SK + buf * 12288;
    glds16(kgp + (size_t)t * 4096 + tid * 8, dst + tid * 8);
    glds16(kpp + (size_t)t * 4096 + tid * 8, dst + 4096 + tid * 8);
    glds16(vgp + (size_t)t * 4096 + tid * 8, dst + 8192 + tid * 8);
  };

  f32x4 oa[4][4] = {};
  float lpart[4] = {0.f, 0.f, 0.f, 0.f};
  union VP8 { half8_t h8; struct { half4_t lo, hi; } p; };

  auto tile_body = [&](int t, const _Float16* Bse) {
    const int dk = t * 64 - q0 - qw * 64;   // 64-granular
    const int f0 = kw * 2;

    // ---- all LDS reads up front (12x b128) ----
    half8_t kf0[4], kf1[4], vc[4];
    kf0[0] = *(const half8_t*)&Bse[f0 * 1024 + lane * 8];
    kf0[1] = *(const half8_t*)&Bse[f0 * 1024 + 512 + lane * 8];
    kf0[2] = *(const half8_t*)&Bse[4096 + f0 * 1024 + lane * 8];
    kf0[3] = *(const half8_t*)&Bse[4096 + f0 * 1024 + 512 + lane * 8];
    kf1[0] = *(const half8_t*)&Bse[(f0 + 1) * 1024 + lane * 8];
    kf1[1] = *(const half8_t*)&Bse[(f0 + 1) * 1024 + 512 + lane * 8];
    kf1[2] = *(const half8_t*)&Bse[4096 + (f0 + 1) * 1024 + lane * 8];
    kf1[3] = *(const half8_t*)&Bse[4096 + (f0 + 1) * 1024 + 512 + lane * 8];
    #pragma unroll
    for (int d = 0; d < 4; ++d)
      vc[d] = *(const half8_t*)&Bse[8192 + (kw * 4 + d) * 512 + lane * 8];

    // ---- bias init for both sub-tiles ----
    f32x4 s0[4], s1[4];
    if (dk < -128 || dk > 128) {
      float c = (dk < 0) ? b_lo : b_hi;
      #pragma unroll
      for (int qt = 0; qt < 4; ++qt) { s0[qt] = {c, c, c, c}; s1[qt] = {c, c, c, c}; }
    } else {
      #pragma unroll
      for (int qt = 0; qt < 4; ++qt) {
        int dbase = dk + f0 * 16 + quad * 4 - qt * 16 - l16 + 192;
        #pragma unroll
        for (int r = 0; r < 4; ++r) s0[qt][r] = biasl[dbase + r];
        #pragma unroll
        for (int r = 0; r < 4; ++r) s1[qt][r] = biasl[dbase + 16 + r];
      }
    }

    // ---- 32 QK MFMAs, one cluster ----
    __builtin_amdgcn_s_setprio(1);
    #pragma unroll
    for (int qt = 0; qt < 4; ++qt)
      #pragma unroll
      for (int kf = 0; kf < 4; ++kf)
        s0[qt] = mfma_qk(kf0[kf], qf[kf][qt], s0[qt]);
    #pragma unroll
    for (int qt = 0; qt < 4; ++qt)
      #pragma unroll
      for (int kf = 0; kf < 4; ++kf)
        s1[qt] = mfma_qk(kf1[kf], qf[kf][qt], s1[qt]);
    __builtin_amdgcn_s_setprio(0);

    // ---- exp both sub-tiles (same lpart fp order) ----
    VP8 pc[4];
    #pragma unroll
    for (int qt = 0; qt < 4; ++qt) {
      float p0 = fexp2(s0[qt][0]), p1 = fexp2(s0[qt][1]);
      float p2 = fexp2(s0[qt][2]), p3 = fexp2(s0[qt][3]);
      lpart[qt] += (p0 + p1) + (p2 + p3);
      union { half2_t h2[2]; half4_t h4; } u;
      u.h2[0] = __builtin_bit_cast(half2_t, __builtin_amdgcn_cvt_pkrtz(p0, p1));
      u.h2[1] = __builtin_bit_cast(half2_t, __builtin_amdgcn_cvt_pkrtz(p2, p3));
      pc[qt].p.lo = u.h4;
    }
    #pragma unroll
    for (int qt = 0; qt < 4; ++qt) {
      float p0 = fexp2(s1[qt][0]), p1 = fexp2(s1[qt][1]);
      float p2 = fexp2(s1[qt][2]), p3 = fexp2(s1[qt][3]);
      lpart[qt] += (p0 + p1) + (p2 + p3);
      union { half2_t h2[2]; half4_t h4; } u;
      u.h2[0] = __builtin_bit_cast(half2_t, __builtin_amdgcn_cvt_pkrtz(p0, p1));
      u.h2[1] = __builtin_bit_cast(half2_t, __builtin_amdgcn_cvt_pkrtz(p2, p3));
      pc[qt].p.hi = u.h4;
    }

    // ---- PV ----
    __builtin_amdgcn_s_setprio(1);
    #pragma unroll
    for (int d = 0; d < 4; ++d)
      #pragma unroll
      for (int qt = 0; qt < 4; ++qt)
        oa[d][qt] = mfma_qk(vc[d], pc[qt].h8, oa[d][qt]);
    __builtin_amdgcn_s_setprio(0);
  };

  stage(0, 0); stage(1, 1);
  __syncthreads();   // also covers biasl

  #pragma unroll 1
  for (int p = 0; p < 16; ++p) {
    const int base = (p & 1) * 2;          // compute buffers {base, base+1}
    if (p != 15) { stage(2 * p + 2, base ^ 2); stage(2 * p + 3, (base ^ 2) + 1); }
    tile_body(2 * p,     SK + base * 12288);
    tile_body(2 * p + 1, SK + (base + 1) * 12288);
    __syncthreads();   // pair p+1 landed; buffers {base,base+1} free
  }

  // ---- cross-half combine (kw=1 -> LDS, kw=0 adds + stores), 2 d-rounds ----
  #pragma unroll
  for (int qt = 0; qt < 4; ++qt) {
    lpart[qt] += __shfl_xor(lpart[qt], 16, 64);
    lpart[qt] += __shfl_xor(lpart[qt], 32, 64);
  }
  if (kw == 1) {
    if (quad == 0) {
      #pragma unroll
      for (int qt = 0; qt < 4; ++qt) lred[qw * 64 + qt * 16 + l16] = lpart[qt];
    }
    #pragma unroll
    for (int d = 0; d < 2; ++d)
      #pragma unroll
      for (int qt = 0; qt < 4; ++qt)
        *(f32x4*)&ored[(qw * 64 + qt * 16 + l16) * 36 + d * 16 + quad * 4] = oa[d][qt];
  }
  __syncthreads();
  float inv[4];
  if (kw == 0) {
    #pragma unroll
    for (int qt = 0; qt < 4; ++qt)
      inv[qt] = 1.f / (lpart[qt] + lred[qw * 64 + qt * 16 + l16]);
    #pragma unroll
    for (int d = 0; d < 2; ++d)
      #pragma unroll
      for (int qt = 0; qt < 4; ++qt) {
        f32x4 p = *(const f32x4*)&ored[(qw * 64 + qt * 16 + l16) * 36 + d * 16 + quad * 4];
        f32x4 sum = oa[d][qt] + p;
        sum[0] *= inv[qt]; sum[1] *= inv[qt]; sum[2] *= inv[qt]; sum[3] *= inv[qt];
        *(f32x4*)(out + (size_t)(b * S_LEN + qbase + qt * 16 + l16) * 1024 +
                  h * 64 + d * 16 + quad * 4) = sum;
      }
  }
  __syncthreads();
  if (kw == 1) {
    #pragma unroll
    for (int d = 2; d < 4; ++d)
      #pragma unroll
      for (int qt = 0; qt < 4; ++qt)
        *(f32x4*)&ored[(qw * 64 + qt * 16 + l16) * 36 + (d - 2) * 16 + quad * 4] = oa[d][qt];
  }
  __syncthreads();
  if (kw == 0) {
    #pragma unroll
    for (int d = 2; d < 4; ++d)
      #pragma unroll
      for (int qt = 0; qt < 4; ++qt) {
        f32x4 p = *(const f32x4*)&ored[(qw * 64 + qt * 16 + l16) * 36 + (d - 2) * 16 + quad * 4];
        f32x4 sum = oa[d][qt] + p;
        sum[0] *= inv[qt]; sum[1] *= inv[qt]; sum[2] *= inv[qt]; sum[3] *= inv[qt];
        *(f32x4*)(out + (size_t)(b * S_LEN + qbase + qt * 16 + l16) * 1024 +
                  h * 64 + (d - 2) * 16 + quad * 4 + 32) = sum;
      }
  }
}

extern "C" void kernel_launch(void* const* d_in, const int* in_sizes, int n_in,
                              void* d_out, int out_size, void* d_ws, size_t ws_size,
                              hipStream_t stream) {
  (void)in_sizes; (void)n_in; (void)out_size; (void)ws_size;
  const float* x          = (const float*)d_in[0];
  const float* pos_embed  = (const float*)d_in[1];
  const float* W_pos_kq   = (const float*)d_in[2];
  const float* W_tok_kqv  = (const float*)d_in[3];
  const float* bias_table = (const float*)d_in[4];
  float* out = (float*)d_out;

  _Float16* ws = (_Float16*)d_ws;
  _Float16* pos_f  = ws;                     // 2,097,152
  _Float16* wt_pos = ws + 2097152;           // 2,097,152
  _Float16* x_f    = ws + 4194304;           // 4,194,304
  _Float16* wt_tok = ws + 8388608;           // 3,145,728
  _Float16* KG     = ws + 11534336;          // 4,194,304
  _Float16* KGP    = ws + 15728640;          // 2,097,152
  _Float16* VG     = ws + 17825792;          // 4,194,304
  _Float16* QRt    = ws + 22020096;          // 4,194,304
  _Float16* QRp    = ws + 26214400;          // 2,097,152
  // total 28,311,552 halfs = 56.6 MB

  const float QSCALE = 0.08838834764831845f * LOG2E;  // 1/sqrt(2*64) * log2e

  prep_kernel<<<7424, 256, 0, stream>>>(x, pos_embed, W_pos_kq, W_tok_kqv,
                                        x_f, pos_f, wt_pos, wt_tok);
  gemm_all_kernel<<<512, 512, 0, stream>>>(pos_f, wt_pos, x_f, wt_tok,
                                           KGP, QRp, KG, QRt, VG, QSCALE);
  flash_kernel<<<256, 512, 0, stream>>>(QRt, QRp, KG, KGP, VG, bias_table, out);
}

// Round 13
// 179.986 us; speedup vs baseline: 1.1113x; 1.0337x over previous
//
#include <hip/hip_runtime.h>

#define S_LEN 2048
#define NH 16
#define LOG2E 1.4426950408889634f

typedef _Float16 half8_t __attribute__((ext_vector_type(8)));
typedef _Float16 half4_t __attribute__((ext_vector_type(4)));
typedef _Float16 half2_t __attribute__((ext_vector_type(2)));
typedef float f32x4 __attribute__((ext_vector_type(4)));

__device__ __forceinline__ f32x4 mfma_qk(half8_t a, half8_t b, f32x4 c) {
  return __builtin_amdgcn_mfma_f32_16x16x32_f16(a, b, c, 0, 0, 0);
}
__device__ __forceinline__ void glds16(const void* g, void* l) {
  __builtin_amdgcn_global_load_lds(
      (const __attribute__((address_space(1))) unsigned int*)g,
      (__attribute__((address_space(3))) unsigned int*)l, 16, 0, 0);
}
__device__ __forceinline__ float fexp2(float x) {
#if __has_builtin(__builtin_amdgcn_exp2f)
  return __builtin_amdgcn_exp2f(x);   // raw v_exp_f32, 1 instr
#else
  return exp2f(x);
#endif
}

// ---------------- fused prep v2: 16B/lane both directions ----------------
// R12 subtraction analysis: prep ~55-60us for only ~70MB traffic (1.2 TB/s =
// 19% of achievable) -- transaction-size limited (2-4B/lane), not BW limited.
// Rewrite: cvt = 8 floats/thread (2x float4 -> half8); transpose reads tile
// at float4/lane, writes at half8/lane (per-lane 8-elem LDS column gather,
// 2-way bank alias = free). Same rounding -> bit-identical outputs.
// blocks [0,3072): cvt (pos_embed 262144 half8s, then x 524288)
// blocks [3072,3584): W_pos transpose; [3584,4352): W_tok transpose
__global__ __launch_bounds__(256) void prep_kernel(const float* __restrict__ x,
                                                   const float* __restrict__ pos_embed,
                                                   const float* __restrict__ W_pos,
                                                   const float* __restrict__ W_tok,
                                                   _Float16* __restrict__ x_f,
                                                   _Float16* __restrict__ pos_f,
                                                   _Float16* __restrict__ wt_pos,
                                                   _Float16* __restrict__ wt_tok) {
  __shared__ float tile[64][65];
  const int bid = blockIdx.x, tid = threadIdx.x;
  if (bid < 3072) {
    int id = bid * 256 + tid;          // one half8 (8 floats) per thread
    const float* src; _Float16* dst;
    if (id < 262144) { src = pos_embed; dst = pos_f; }
    else { id -= 262144; src = x; dst = x_f; }
    float4 f0 = ((const float4*)src)[id * 2];
    float4 f1 = ((const float4*)src)[id * 2 + 1];
    half8_t o = {(_Float16)f0.x, (_Float16)f0.y, (_Float16)f0.z, (_Float16)f0.w,
                 (_Float16)f1.x, (_Float16)f1.y, (_Float16)f1.z, (_Float16)f1.w};
    ((half8_t*)dst)[id] = o;
    return;
  }
  // weight transpose fp32 [K,N] -> fp16 [N,K], K=1024, 64x64 tiles
  const float* W; _Float16* Wt; int N, nx, ky;
  if (bid < 3584) { W = W_pos; Wt = wt_pos; N = 2048; int t = bid - 3072; nx = t & 31; ky = t >> 5; }
  else            { W = W_tok; Wt = wt_tok; N = 3072; int t = bid - 3584; nx = t % 48; ky = t / 48; }
  int k0 = ky * 64, n0 = nx * 64;
  // read: 16B/lane coalesced (4 rows per wave)
  #pragma unroll
  for (int it = 0; it < 4; ++it) {
    int idx = it * 256 + tid;
    int row = idx >> 4, c4 = (idx & 15) * 4;
    float4 f = *(const float4*)&W[(size_t)(k0 + row) * N + n0 + c4];
    tile[row][c4]     = f.x;
    tile[row][c4 + 1] = f.y;
    tile[row][c4 + 2] = f.z;
    tile[row][c4 + 3] = f.w;
  }
  __syncthreads();
  // write: 16B/lane coalesced (8 n-rows per wave); LDS column gather is
  // 2-way bank alias with the 65-float pad (free, m136)
  #pragma unroll
  for (int it = 0; it < 2; ++it) {
    int idx = it * 256 + tid;
    int n = idx >> 3, k8 = (idx & 7) * 8;
    half8_t o;
    #pragma unroll
    for (int i = 0; i < 8; ++i) o[i] = (_Float16)tile[k8 + i][n];
    *(half8_t*)&Wt[(size_t)(n0 + n) * 1024 + k0 + k8] = o;
  }
}

// ---------------- merged fp16 GEMM (pos + tok), fragment-layout epilogues ------
// R12-verified: BM=256 x BN=128, 512 blocks x 512 threads (8 waves = 4M x 2N),
// each wave owns a 64x64 output tile -> all epilogues preserved verbatim.
// 2-phase dbuf loop (R7-verified) unchanged.
// blocks [0,128):  pos gemm 2048x2048
// blocks [128,512): tok gemm 4096x3072
__global__ __launch_bounds__(512) void gemm_all_kernel(const _Float16* __restrict__ pos_f,
                                                       const _Float16* __restrict__ wt_pos,
                                                       const _Float16* __restrict__ x_f,
                                                       const _Float16* __restrict__ wt_tok,
                                                       _Float16* __restrict__ KGP,
                                                       _Float16* __restrict__ QRp,
                                                       _Float16* __restrict__ KG,
                                                       _Float16* __restrict__ QRt,
                                                       _Float16* __restrict__ VG,
                                                       float qscale) {
  __shared__ _Float16 SMem[24576];       // 48 KB: 2x (A 16KB | B 8KB) double-buffer
  _Float16* buf0 = SMem;                 // [0,8192)=A  [8192,12288)=B
  _Float16* buf1 = SMem + 12288;

  const int bid = blockIdx.x, tid = threadIdx.x;
  const _Float16 *A, *Bt; _Float16 *kg, *qr, *vg;
  int m0, n0;
  if (bid < 128) {
    A = pos_f; Bt = wt_pos; kg = KGP; qr = QRp; vg = nullptr;
    m0 = (bid >> 4) * 256; n0 = (bid & 15) * 128;
  } else {
    int t = bid - 128;
    A = x_f; Bt = wt_tok; kg = KG; qr = QRt; vg = VG;
    m0 = (t / 24) * 256; n0 = (t % 24) * 128;
  }
  const int K = 1024;

  const int wave = tid >> 6, lane = tid & 63;
  const int quad = lane >> 4, l16 = lane & 15;
  const int wm = (wave >> 1) * 64, wn = (wave & 1) * 64;

  f32x4 acc[4][4] = {};
  const int fa0 = tid, fa1 = tid + 512;            // A: 1024 x 16B chunks
  const int ra0 = fa0 >> 2, ca0 = fa0 & 3;
  const int ra1 = fa1 >> 2, ca1 = fa1 & 3;
  const int rb = tid >> 2, cb = tid & 3;           // B: 512 x 16B chunks

  auto stage = [&](int ko, _Float16* buf) {
    glds16(A + (size_t)(m0 + ra0) * K + ko + ca0 * 8, &buf[fa0 * 8]);
    glds16(A + (size_t)(m0 + ra1) * K + ko + ca1 * 8, &buf[fa1 * 8]);
    glds16(Bt + (size_t)(n0 + rb) * K + ko + cb * 8, &buf[8192 + tid * 8]);
  };
  auto kstep = [&](const _Float16* buf) {
    half8_t af[4], bfv[4];
    #pragma unroll
    for (int t = 0; t < 4; ++t) {
      af[t]  = *(const half8_t*)&buf[(wm + t * 16 + l16) * 32 + quad * 8];
      bfv[t] = *(const half8_t*)&buf[8192 + (wn + t * 16 + l16) * 32 + quad * 8];
    }
    #pragma unroll
    for (int mi = 0; mi < 4; ++mi)
      #pragma unroll
      for (int ni = 0; ni < 4; ++ni)
        acc[mi][ni] = mfma_qk(af[mi], bfv[ni], acc[mi][ni]);
  };

  stage(0, buf0);
  __syncthreads();
  #pragma unroll 1
  for (int ko = 0; ko < K; ko += 64) {
    stage(ko + 32, buf1);                 // next tile issues before compute
    kstep(buf0);
    __syncthreads();                      // readers done + buf1 loads landed
    if (ko + 64 < K) stage(ko + 64, buf0);
    kstep(buf1);
    __syncthreads();
  }
  // last barrier above also protects SMem before epilogue scratch reuse

  const int n_base = n0 + wn, m_base = m0 + wm;   // both 64-aligned
  const int bb = m_base >> 11;
  const int tile16 = (m_base & 2047) >> 6;

  if (n_base >= 2048) {
    // V region (tok only), pair-interleaved:
    // idx = ((mi>>1)*4 + ni)*512 + quad*128 + l16*8 + (mi&1)*4
    int hh = (n_base >> 6) & 15;
    _Float16* dstb = vg + (size_t)((bb * 16 + hh) * 32 + tile16) * 4096;
    #pragma unroll
    for (int mi = 0; mi < 4; ++mi)
      #pragma unroll
      for (int ni = 0; ni < 4; ++ni) {
        union { ushort4 u; _Float16 h[4]; } pk;
        #pragma unroll
        for (int r = 0; r < 4; ++r) pk.h[r] = (_Float16)acc[mi][ni][r];
        *(ushort4*)(dstb + ((mi >> 1) * 4 + ni) * 512 + quad * 128 + l16 * 8 +
                    (mi & 1) * 4) = pk.u;
      }
  } else if (n_base >= 1024) {
    // Q region: row-major, scaled
    #pragma unroll
    for (int mi = 0; mi < 4; ++mi)
      #pragma unroll
      for (int ni = 0; ni < 4; ++ni)
        #pragma unroll
        for (int r = 0; r < 4; ++r) {
          int m = m_base + mi * 16 + quad * 4 + r;
          int col = n_base - 1024 + ni * 16 + l16;
          qr[(size_t)m * 1024 + col] = (_Float16)(acc[mi][ni][r] * qscale);
        }
  } else {
    // K region: in-lane dim-transpose, 2 rounds of 32 keys through 4 KB/wave scratch
    int hh = n_base >> 6;
    int bhk = vg ? (bb * 16 + hh) : hh;
    _Float16* dstb = kg + (size_t)(bhk * 32 + tile16) * 4096;
    _Float16* Tr = SMem + wave * 2048;       // per-wave private 4 KB (8 waves = 32KB)
    #pragma unroll
    for (int p = 0; p < 2; ++p) {
      #pragma unroll
      for (int mi2 = 0; mi2 < 2; ++mi2) {
        int mi = p * 2 + mi2;
        #pragma unroll
        for (int ni = 0; ni < 4; ++ni)
          #pragma unroll
          for (int r = 0; r < 4; ++r) {
            int keyp = mi2 * 16 + quad * 4 + r;            // 0..31
            int dim = ni * 16 + l16;
            int col = (((dim >> 3) ^ (keyp & 7)) << 3) | (dim & 7);
            Tr[keyp * 64 + col] = (_Float16)acc[mi][ni][r];
          }
      }
      #pragma unroll
      for (int j = 0; j < 4; ++j) {
        int wkp = j >> 1, kfl = j & 1;
        int wk = p * 2 + wkp;
        half8_t v = *(const half8_t*)&Tr[(wkp * 16 + l16) * 64 +
                                         (((kfl * 4 + quad) ^ (l16 & 7)) << 3)];
        *(half8_t*)(dstb + wk * 1024 + kfl * 512 + quad * 128 + l16 * 8) = v;
      }
    }
  }
}

// ---------------- fused flash attention v12 (R10-verified BEST) --------
// FROZEN. 256 q-rows/block, grid 256, 8 waves (2kw x 4qw), pair-deep LDS
// staging (4 tile-buffers, 1 barrier per 2 tiles), batched tile body, K=32 PV
// fusion. R11 proved cross-block TLP does NOT help (MfmaUtil pinned ~35%
// across 4 structures -- per-wave QK->exp->PV chain is the limiter).
__global__ __launch_bounds__(512, 1) void flash_kernel(const _Float16* __restrict__ QRt,
                                                       const _Float16* __restrict__ QRp,
                                                       const _Float16* __restrict__ KG,
                                                       const _Float16* __restrict__ KGP,
                                                       const _Float16* __restrict__ VG,
                                                       const float* __restrict__ bias_table,
                                                       float* __restrict__ out) {
  __shared__ __align__(16) unsigned char SM[100864];
  _Float16* SK = (_Float16*)SM;             // [4][12288] halfs: Ktok|Kpos|V, 4 tile-buffers
  float* ored  = (float*)SM;                // [4][64][36] fp32, overlay after loop
  float* biasl = (float*)(SM + 98304);      // 384 floats
  float* lred  = (float*)(SM + 99840);      // [4][64] floats

  const int tid = threadIdx.x;
  const int wave = tid >> 6, lane = tid & 63;
  const int quad = lane >> 4, l16 = lane & 15;
  const int qw = wave & 3, kw = wave >> 2;
  const int lbid = blockIdx.x;
  const int q0 = ((lbid >> 3) & 7) * 256;        // 8 q-blocks per bh
  const int bh = (lbid & 7) + 8 * (lbid >> 6);   // bh's q-blocks share one XCD
  const int b = bh >> 4, h = bh & 15;

  if (tid < 384) {
    int i = tid;
    int delta = i - 192;
    int n = -delta;
    int ret = (n < 0) ? 16 : 0;
    int na = (n < 0) ? -n : n;
    int bkt;
    if (na < 8) bkt = na;
    else {
      int s2 = (na >= 12) + (na >= 16) + (na >= 23) + (na >= 32) +
               (na >= 46) + (na >= 64) + (na >= 91) + (na >= 128);
      bkt = 8 + s2; if (bkt > 15) bkt = 15;
    }
    bkt += ret;
    biasl[i] = bias_table[(size_t)(2048 + bkt) * NH + h] * LOG2E;
  }
  const float b_lo = bias_table[(2048 + 15) * NH + h] * LOG2E;
  const float b_hi = bias_table[(2048 + 31) * NH + h] * LOG2E;

  // Q fragments (pre-scaled in gemm epilogue); wave's rows = q0+qw*64+qt*16+l16
  const int qbase = q0 + qw * 64;
  half8_t qf[4][4];
  {
    const _Float16* tq = QRt + (size_t)(b * S_LEN + qbase + l16) * 1024 + h * 64 + quad * 8;
    const _Float16* pq = QRp + (size_t)(qbase + l16) * 1024 + h * 64 + quad * 8;
    #pragma unroll
    for (int qt = 0; qt < 4; ++qt)
      #pragma unroll
      for (int kf = 0; kf < 2; ++kf) {
        qf[kf][qt]     = *(const half8_t*)(tq + (size_t)qt * 16 * 1024 + kf * 32);
        qf[kf + 2][qt] = *(const half8_t*)(pq + (size_t)qt * 16 * 1024 + kf * 32);
      }
  }

  const _Float16* kgp = KG  + (size_t)bh * 131072;
  const _Float16* kpp = KGP + (size_t)h  * 131072;
  const _Float16* vgp = VG  + (size_t)bh * 131072;

  auto stage = [&](int t, int buf) {
    _Float16* dst = SK + buf * 12288;
    glds16(kgp + (size_t)t * 4096 + tid * 8, dst + tid * 8);
    glds16(kpp + (size_t)t * 4096 + tid * 8, dst + 4096 + tid * 8);
    glds16(vgp + (size_t)t * 4096 + tid * 8, dst + 8192 + tid * 8);
  };

  f32x4 oa[4][4] = {};
  float lpart[4] = {0.f, 0.f, 0.f, 0.f};
  union VP8 { half8_t h8; struct { half4_t lo, hi; } p; };

  auto tile_body = [&](int t, const _Float16* Bse) {
    const int dk = t * 64 - q0 - qw * 64;   // 64-granular
    const int f0 = kw * 2;

    // ---- all LDS reads up front (12x b128) ----
    half8_t kf0[4], kf1[4], vc[4];
    kf0[0] = *(const half8_t*)&Bse[f0 * 1024 + lane * 8];
    kf0[1] = *(const half8_t*)&Bse[f0 * 1024 + 512 + lane * 8];
    kf0[2] = *(const half8_t*)&Bse[4096 + f0 * 1024 + lane * 8];
    kf0[3] = *(const half8_t*)&Bse[4096 + f0 * 1024 + 512 + lane * 8];
    kf1[0] = *(const half8_t*)&Bse[(f0 + 1) * 1024 + lane * 8];
    kf1[1] = *(const half8_t*)&Bse[(f0 + 1) * 1024 + 512 + lane * 8];
    kf1[2] = *(const half8_t*)&Bse[4096 + (f0 + 1) * 1024 + lane * 8];
    kf1[3] = *(const half8_t*)&Bse[4096 + (f0 + 1) * 1024 + 512 + lane * 8];
    #pragma unroll
    for (int d = 0; d < 4; ++d)
      vc[d] = *(const half8_t*)&Bse[8192 + (kw * 4 + d) * 512 + lane * 8];

    // ---- bias init for both sub-tiles ----
    f32x4 s0[4], s1[4];
    if (dk < -128 || dk > 128) {
      float c = (dk < 0) ? b_lo : b_hi;
      #pragma unroll
      for (int qt = 0; qt < 4; ++qt) { s0[qt] = {c, c, c, c}; s1[qt] = {c, c, c, c}; }
    } else {
      #pragma unroll
      for (int qt = 0; qt < 4; ++qt) {
        int dbase = dk + f0 * 16 + quad * 4 - qt * 16 - l16 + 192;
        #pragma unroll
        for (int r = 0; r < 4; ++r) s0[qt][r] = biasl[dbase + r];
        #pragma unroll
        for (int r = 0; r < 4; ++r) s1[qt][r] = biasl[dbase + 16 + r];
      }
    }

    // ---- 32 QK MFMAs, one cluster ----
    __builtin_amdgcn_s_setprio(1);
    #pragma unroll
    for (int qt = 0; qt < 4; ++qt)
      #pragma unroll
      for (int kf = 0; kf < 4; ++kf)
        s0[qt] = mfma_qk(kf0[kf], qf[kf][qt], s0[qt]);
    #pragma unroll
    for (int qt = 0; qt < 4; ++qt)
      #pragma unroll
      for (int kf = 0; kf < 4; ++kf)
        s1[qt] = mfma_qk(kf1[kf], qf[kf][qt], s1[qt]);
    __builtin_amdgcn_s_setprio(0);

    // ---- exp both sub-tiles (same lpart fp order) ----
    VP8 pc[4];
    #pragma unroll
    for (int qt = 0; qt < 4; ++qt) {
      float p0 = fexp2(s0[qt][0]), p1 = fexp2(s0[qt][1]);
      float p2 = fexp2(s0[qt][2]), p3 = fexp2(s0[qt][3]);
      lpart[qt] += (p0 + p1) + (p2 + p3);
      union { half2_t h2[2]; half4_t h4; } u;
      u.h2[0] = __builtin_bit_cast(half2_t, __builtin_amdgcn_cvt_pkrtz(p0, p1));
      u.h2[1] = __builtin_bit_cast(half2_t, __builtin_amdgcn_cvt_pkrtz(p2, p3));
      pc[qt].p.lo = u.h4;
    }
    #pragma unroll
    for (int qt = 0; qt < 4; ++qt) {
      float p0 = fexp2(s1[qt][0]), p1 = fexp2(s1[qt][1]);
      float p2 = fexp2(s1[qt][2]), p3 = fexp2(s1[qt][3]);
      lpart[qt] += (p0 + p1) + (p2 + p3);
      union { half2_t h2[2]; half4_t h4; } u;
      u.h2[0] = __builtin_bit_cast(half2_t, __builtin_amdgcn_cvt_pkrtz(p0, p1));
      u.h2[1] = __builtin_bit_cast(half2_t, __builtin_amdgcn_cvt_pkrtz(p2, p3));
      pc[qt].p.hi = u.h4;
    }

    // ---- PV ----
    __builtin_amdgcn_s_setprio(1);
    #pragma unroll
    for (int d = 0; d < 4; ++d)
      #pragma unroll
      for (int qt = 0; qt < 4; ++qt)
        oa[d][qt] = mfma_qk(vc[d], pc[qt].h8, oa[d][qt]);
    __builtin_amdgcn_s_setprio(0);
  };

  stage(0, 0); stage(1, 1);
  __syncthreads();   // also covers biasl

  #pragma unroll 1
  for (int p = 0; p < 16; ++p) {
    const int base = (p & 1) * 2;          // compute buffers {base, base+1}
    if (p != 15) { stage(2 * p + 2, base ^ 2); stage(2 * p + 3, (base ^ 2) + 1); }
    tile_body(2 * p,     SK + base * 12288);
    tile_body(2 * p + 1, SK + (base + 1) * 12288);
    __syncthreads();   // pair p+1 landed; buffers {base,base+1} free
  }

  // ---- cross-half combine (kw=1 -> LDS, kw=0 adds + stores), 2 d-rounds ----
  #pragma unroll
  for (int qt = 0; qt < 4; ++qt) {
    lpart[qt] += __shfl_xor(lpart[qt], 16, 64);
    lpart[qt] += __shfl_xor(lpart[qt], 32, 64);
  }
  if (kw == 1) {
    if (quad == 0) {
      #pragma unroll
      for (int qt = 0; qt < 4; ++qt) lred[qw * 64 + qt * 16 + l16] = lpart[qt];
    }
    #pragma unroll
    for (int d = 0; d < 2; ++d)
      #pragma unroll
      for (int qt = 0; qt < 4; ++qt)
        *(f32x4*)&ored[(qw * 64 + qt * 16 + l16) * 36 + d * 16 + quad * 4] = oa[d][qt];
  }
  __syncthreads();
  float inv[4];
  if (kw == 0) {
    #pragma unroll
    for (int qt = 0; qt < 4; ++qt)
      inv[qt] = 1.f / (lpart[qt] + lred[qw * 64 + qt * 16 + l16]);
    #pragma unroll
    for (int d = 0; d < 2; ++d)
      #pragma unroll
      for (int qt = 0; qt < 4; ++qt) {
        f32x4 p = *(const f32x4*)&ored[(qw * 64 + qt * 16 + l16) * 36 + d * 16 + quad * 4];
        f32x4 sum = oa[d][qt] + p;
        sum[0] *= inv[qt]; sum[1] *= inv[qt]; sum[2] *= inv[qt]; sum[3] *= inv[qt];
        *(f32x4*)(out + (size_t)(b * S_LEN + qbase + qt * 16 + l16) * 1024 +
                  h * 64 + d * 16 + quad * 4) = sum;
      }
  }
  __syncthreads();
  if (kw == 1) {
    #pragma unroll
    for (int d = 2; d < 4; ++d)
      #pragma unroll
      for (int qt = 0; qt < 4; ++qt)
        *(f32x4*)&ored[(qw * 64 + qt * 16 + l16) * 36 + (d - 2) * 16 + quad * 4] = oa[d][qt];
  }
  __syncthreads();
  if (kw == 0) {
    #pragma unroll
    for (int d = 2; d < 4; ++d)
      #pragma unroll
      for (int qt = 0; qt < 4; ++qt) {
        f32x4 p = *(const f32x4*)&ored[(qw * 64 + qt * 16 + l16) * 36 + (d - 2) * 16 + quad * 4];
        f32x4 sum = oa[d][qt] + p;
        sum[0] *= inv[qt]; sum[1] *= inv[qt]; sum[2] *= inv[qt]; sum[3] *= inv[qt];
        *(f32x4*)(out + (size_t)(b * S_LEN + qbase + qt * 16 + l16) * 1024 +
                  h * 64 + (d - 2) * 16 + quad * 4 + 32) = sum;
      }
  }
}

extern "C" void kernel_launch(void* const* d_in, const int* in_sizes, int n_in,
                              void* d_out, int out_size, void* d_ws, size_t ws_size,
                              hipStream_t stream) {
  (void)in_sizes; (void)n_in; (void)out_size; (void)ws_size;
  const float* x          = (const float*)d_in[0];
  const float* pos_embed  = (const float*)d_in[1];
  const float* W_pos_kq   = (const float*)d_in[2];
  const float* W_tok_kqv  = (const float*)d_in[3];
  const float* bias_table = (const float*)d_in[4];
  float* out = (float*)d_out;

  _Float16* ws = (_Float16*)d_ws;
  _Float16* pos_f  = ws;                     // 2,097,152
  _Float16* wt_pos = ws + 2097152;           // 2,097,152
  _Float16* x_f    = ws + 4194304;           // 4,194,304
  _Float16* wt_tok = ws + 8388608;           // 3,145,728
  _Float16* KG     = ws + 11534336;          // 4,194,304
  _Float16* KGP    = ws + 15728640;          // 2,097,152
  _Float16* VG     = ws + 17825792;          // 4,194,304
  _Float16* QRt    = ws + 22020096;          // 4,194,304
  _Float16* QRp    = ws + 26214400;          // 2,097,152
  // total 28,311,552 halfs = 56.6 MB

  const float QSCALE = 0.08838834764831845f * LOG2E;  // 1/sqrt(2*64) * log2e

  prep_kernel<<<4352, 256, 0, stream>>>(x, pos_embed, W_pos_kq, W_tok_kqv,
                                        x_f, pos_f, wt_pos, wt_tok);
  gemm_all_kernel<<<512, 512, 0, stream>>>(pos_f, wt_pos, x_f, wt_tok,
                                           KGP, QRp, KG, QRt, VG, QSCALE);
  flash_kernel<<<256, 512, 0, stream>>>(QRt, QRp, KG, KGP, VG, bias_table, out);
}

// Round 14
// 179.277 us; speedup vs baseline: 1.1157x; 1.0040x over previous
//
#include <hip/hip_runtime.h>

#define S_LEN 2048
#define NH 16
#define LOG2E 1.4426950408889634f

typedef _Float16 half8_t __attribute__((ext_vector_type(8)));
typedef _Float16 half4_t __attribute__((ext_vector_type(4)));
typedef _Float16 half2_t __attribute__((ext_vector_type(2)));
typedef float f32x4 __attribute__((ext_vector_type(4)));

__device__ __forceinline__ f32x4 mfma_qk(half8_t a, half8_t b, f32x4 c) {
  return __builtin_amdgcn_mfma_f32_16x16x32_f16(a, b, c, 0, 0, 0);
}
__device__ __forceinline__ void glds16(const void* g, void* l) {
  __builtin_amdgcn_global_load_lds(
      (const __attribute__((address_space(1))) unsigned int*)g,
      (__attribute__((address_space(3))) unsigned int*)l, 16, 0, 0);
}
__device__ __forceinline__ float fexp2(float x) {
#if __has_builtin(__builtin_amdgcn_exp2f)
  return __builtin_amdgcn_exp2f(x);   // raw v_exp_f32, 1 instr
#else
  return exp2f(x);
#endif
}

// ---------------- fused prep v3 ----------------
// cvt: fully contiguous addressing (2x float4 loads + 2x half4 stores per
// thread, every instruction lane-contiguous). Transpose unchanged (R13).
// blocks [0,1024): pos_embed cvt; [1024,3072): x cvt
// blocks [3072,3584): W_pos transpose; [3584,4352): W_tok transpose
__global__ __launch_bounds__(256) void prep_kernel(const float* __restrict__ x,
                                                   const float* __restrict__ pos_embed,
                                                   const float* __restrict__ W_pos,
                                                   const float* __restrict__ W_tok,
                                                   _Float16* __restrict__ x_f,
                                                   _Float16* __restrict__ pos_f,
                                                   _Float16* __restrict__ wt_pos,
                                                   _Float16* __restrict__ wt_tok) {
  __shared__ float tile[64][65];
  const int bid = blockIdx.x, tid = threadIdx.x;
  if (bid < 3072) {
    const float* src; _Float16* dst; int base;
    if (bid < 1024) { src = pos_embed; dst = pos_f; base = bid * 512; }
    else { src = x; dst = x_f; base = (bid - 1024) * 512; }
    float4 f0 = ((const float4*)src)[base + tid];
    float4 f1 = ((const float4*)src)[base + 256 + tid];
    half4_t o0 = {(_Float16)f0.x, (_Float16)f0.y, (_Float16)f0.z, (_Float16)f0.w};
    half4_t o1 = {(_Float16)f1.x, (_Float16)f1.y, (_Float16)f1.z, (_Float16)f1.w};
    ((half4_t*)dst)[base + tid] = o0;
    ((half4_t*)dst)[base + 256 + tid] = o1;
    return;
  }
  // weight transpose fp32 [K,N] -> fp16 [N,K], K=1024, 64x64 tiles
  const float* W; _Float16* Wt; int N, nx, ky;
  if (bid < 3584) { W = W_pos; Wt = wt_pos; N = 2048; int t = bid - 3072; nx = t & 31; ky = t >> 5; }
  else            { W = W_tok; Wt = wt_tok; N = 3072; int t = bid - 3584; nx = t % 48; ky = t / 48; }
  int k0 = ky * 64, n0 = nx * 64;
  // read: 16B/lane coalesced (4 rows per wave)
  #pragma unroll
  for (int it = 0; it < 4; ++it) {
    int idx = it * 256 + tid;
    int row = idx >> 4, c4 = (idx & 15) * 4;
    float4 f = *(const float4*)&W[(size_t)(k0 + row) * N + n0 + c4];
    tile[row][c4]     = f.x;
    tile[row][c4 + 1] = f.y;
    tile[row][c4 + 2] = f.z;
    tile[row][c4 + 3] = f.w;
  }
  __syncthreads();
  // write: 16B/lane coalesced; LDS column gather is 2-way bank alias (free)
  #pragma unroll
  for (int it = 0; it < 2; ++it) {
    int idx = it * 256 + tid;
    int n = idx >> 3, k8 = (idx & 7) * 8;
    half8_t o;
    #pragma unroll
    for (int i = 0; i < 8; ++i) o[i] = (_Float16)tile[k8 + i][n];
    *(half8_t*)&Wt[(size_t)(n0 + n) * 1024 + k0 + k8] = o;
  }
}

// ---------------- merged fp16 GEMM (pos + tok), fragment-layout epilogues ------
// R12 geometry (BM=256 x BN=128, 512 blocks x 512 threads, wave = 64x64 tile)
// + NEW: T2 LDS XOR-swizzle. The old layout's ds_read_b128 was an 8-WAY bank
// conflict (rows 64B apart -> 16 lanes on 2 banks). Fix per rule #21: glds16
// dest stays LINEAR; the per-lane GLOBAL source column is pre-permuted
// (c' = c ^ ((r>>1)&3)) and the LDS read applies the same XOR
// (quad ^ ((l16>>1)&3)) -> 16 lanes cover all 8 slots twice = 2-way = free.
// Coalescing preserved (4 lanes sharing a row permute within one 64B segment).
__global__ __launch_bounds__(512) void gemm_all_kernel(const _Float16* __restrict__ pos_f,
                                                       const _Float16* __restrict__ wt_pos,
                                                       const _Float16* __restrict__ x_f,
                                                       const _Float16* __restrict__ wt_tok,
                                                       _Float16* __restrict__ KGP,
                                                       _Float16* __restrict__ QRp,
                                                       _Float16* __restrict__ KG,
                                                       _Float16* __restrict__ QRt,
                                                       _Float16* __restrict__ VG,
                                                       float qscale) {
  __shared__ _Float16 SMem[24576];       // 48 KB: 2x (A 16KB | B 8KB) double-buffer
  _Float16* buf0 = SMem;                 // [0,8192)=A  [8192,12288)=B
  _Float16* buf1 = SMem + 12288;

  const int bid = blockIdx.x, tid = threadIdx.x;
  const _Float16 *A, *Bt; _Float16 *kg, *qr, *vg;
  int m0, n0;
  if (bid < 128) {
    A = pos_f; Bt = wt_pos; kg = KGP; qr = QRp; vg = nullptr;
    m0 = (bid >> 4) * 256; n0 = (bid & 15) * 128;
  } else {
    int t = bid - 128;
    A = x_f; Bt = wt_tok; kg = KG; qr = QRt; vg = VG;
    m0 = (t / 24) * 256; n0 = (t % 24) * 128;
  }
  const int K = 1024;

  const int wave = tid >> 6, lane = tid & 63;
  const int quad = lane >> 4, l16 = lane & 15;
  const int wm = (wave >> 1) * 64, wn = (wave & 1) * 64;

  f32x4 acc[4][4] = {};
  // A: 1024 x 16B chunks; source col pre-swizzled so linear LDS slot (r,c)
  // holds A[r][c ^ ((r>>1)&3)]
  const int fa0 = tid, fa1 = tid + 512;
  const int ra0 = fa0 >> 2, ca0 = (fa0 & 3) ^ ((ra0 >> 1) & 3);
  const int ra1 = fa1 >> 2, ca1 = (fa1 & 3) ^ ((ra1 >> 1) & 3);
  const int rb = tid >> 2,  cbp = (tid & 3) ^ ((rb >> 1) & 3);
  const int rsw = (l16 >> 1) & 3;        // read-side XOR (row low bits = l16)

  auto stage = [&](int ko, _Float16* buf) {
    glds16(A + (size_t)(m0 + ra0) * K + ko + ca0 * 8, &buf[fa0 * 8]);
    glds16(A + (size_t)(m0 + ra1) * K + ko + ca1 * 8, &buf[fa1 * 8]);
    glds16(Bt + (size_t)(n0 + rb) * K + ko + cbp * 8, &buf[8192 + tid * 8]);
  };
  auto kstep = [&](const _Float16* buf) {
    half8_t af[4], bfv[4];
    #pragma unroll
    for (int t = 0; t < 4; ++t) {
      af[t]  = *(const half8_t*)&buf[(wm + t * 16 + l16) * 32 + (quad ^ rsw) * 8];
      bfv[t] = *(const half8_t*)&buf[8192 + (wn + t * 16 + l16) * 32 + (quad ^ rsw) * 8];
    }
    #pragma unroll
    for (int mi = 0; mi < 4; ++mi)
      #pragma unroll
      for (int ni = 0; ni < 4; ++ni)
        acc[mi][ni] = mfma_qk(af[mi], bfv[ni], acc[mi][ni]);
  };

  stage(0, buf0);
  __syncthreads();
  #pragma unroll 1
  for (int ko = 0; ko < K; ko += 64) {
    stage(ko + 32, buf1);                 // next tile issues before compute
    kstep(buf0);
    __syncthreads();                      // readers done + buf1 loads landed
    if (ko + 64 < K) stage(ko + 64, buf0);
    kstep(buf1);
    __syncthreads();
  }
  // last barrier above also protects SMem before epilogue scratch reuse

  const int n_base = n0 + wn, m_base = m0 + wm;   // both 64-aligned
  const int bb = m_base >> 11;
  const int tile16 = (m_base & 2047) >> 6;

  if (n_base >= 2048) {
    // V region (tok only), pair-interleaved:
    // idx = ((mi>>1)*4 + ni)*512 + quad*128 + l16*8 + (mi&1)*4
    int hh = (n_base >> 6) & 15;
    _Float16* dstb = vg + (size_t)((bb * 16 + hh) * 32 + tile16) * 4096;
    #pragma unroll
    for (int mi = 0; mi < 4; ++mi)
      #pragma unroll
      for (int ni = 0; ni < 4; ++ni) {
        union { ushort4 u; _Float16 h[4]; } pk;
        #pragma unroll
        for (int r = 0; r < 4; ++r) pk.h[r] = (_Float16)acc[mi][ni][r];
        *(ushort4*)(dstb + ((mi >> 1) * 4 + ni) * 512 + quad * 128 + l16 * 8 +
                    (mi & 1) * 4) = pk.u;
      }
  } else if (n_base >= 1024) {
    // Q region: row-major, scaled
    #pragma unroll
    for (int mi = 0; mi < 4; ++mi)
      #pragma unroll
      for (int ni = 0; ni < 4; ++ni)
        #pragma unroll
        for (int r = 0; r < 4; ++r) {
          int m = m_base + mi * 16 + quad * 4 + r;
          int col = n_base - 1024 + ni * 16 + l16;
          qr[(size_t)m * 1024 + col] = (_Float16)(acc[mi][ni][r] * qscale);
        }
  } else {
    // K region: in-lane dim-transpose, 2 rounds of 32 keys through 4 KB/wave scratch
    int hh = n_base >> 6;
    int bhk = vg ? (bb * 16 + hh) : hh;
    _Float16* dstb = kg + (size_t)(bhk * 32 + tile16) * 4096;
    _Float16* Tr = SMem + wave * 2048;       // per-wave private 4 KB (8 waves = 32KB)
    #pragma unroll
    for (int p = 0; p < 2; ++p) {
      #pragma unroll
      for (int mi2 = 0; mi2 < 2; ++mi2) {
        int mi = p * 2 + mi2;
        #pragma unroll
        for (int ni = 0; ni < 4; ++ni)
          #pragma unroll
          for (int r = 0; r < 4; ++r) {
            int keyp = mi2 * 16 + quad * 4 + r;            // 0..31
            int dim = ni * 16 + l16;
            int col = (((dim >> 3) ^ (keyp & 7)) << 3) | (dim & 7);
            Tr[keyp * 64 + col] = (_Float16)acc[mi][ni][r];
          }
      }
      #pragma unroll
      for (int j = 0; j < 4; ++j) {
        int wkp = j >> 1, kfl = j & 1;
        int wk = p * 2 + wkp;
        half8_t v = *(const half8_t*)&Tr[(wkp * 16 + l16) * 64 +
                                         (((kfl * 4 + quad) ^ (l16 & 7)) << 3)];
        *(half8_t*)(dstb + wk * 1024 + kfl * 512 + quad * 128 + l16 * 8) = v;
      }
    }
  }
}

// ---------------- fused flash attention v12 (R10-verified BEST, FROZEN) --------
// 256 q-rows/block, grid 256, 8 waves (2kw x 4qw), pair-deep LDS staging
// (4 tile-buffers, 1 barrier per 2 tiles), batched tile body, K=32 PV fusion.
__global__ __launch_bounds__(512, 1) void flash_kernel(const _Float16* __restrict__ QRt,
                                                       const _Float16* __restrict__ QRp,
                                                       const _Float16* __restrict__ KG,
                                                       const _Float16* __restrict__ KGP,
                                                       const _Float16* __restrict__ VG,
                                                       const float* __restrict__ bias_table,
                                                       float* __restrict__ out) {
  __shared__ __align__(16) unsigned char SM[100864];
  _Float16* SK = (_Float16*)SM;             // [4][12288] halfs: Ktok|Kpos|V, 4 tile-buffers
  float* ored  = (float*)SM;                // [4][64][36] fp32, overlay after loop
  float* biasl = (float*)(SM + 98304);      // 384 floats
  float* lred  = (float*)(SM + 99840);      // [4][64] floats

  const int tid = threadIdx.x;
  const int wave = tid >> 6, lane = tid & 63;
  const int quad = lane >> 4, l16 = lane & 15;
  const int qw = wave & 3, kw = wave >> 2;
  const int lbid = blockIdx.x;
  const int q0 = ((lbid >> 3) & 7) * 256;        // 8 q-blocks per bh
  const int bh = (lbid & 7) + 8 * (lbid >> 6);   // bh's q-blocks share one XCD
  const int b = bh >> 4, h = bh & 15;

  if (tid < 384) {
    int i = tid;
    int delta = i - 192;
    int n = -delta;
    int ret = (n < 0) ? 16 : 0;
    int na = (n < 0) ? -n : n;
    int bkt;
    if (na < 8) bkt = na;
    else {
      int s2 = (na >= 12) + (na >= 16) + (na >= 23) + (na >= 32) +
               (na >= 46) + (na >= 64) + (na >= 91) + (na >= 128);
      bkt = 8 + s2; if (bkt > 15) bkt = 15;
    }
    bkt += ret;
    biasl[i] = bias_table[(size_t)(2048 + bkt) * NH + h] * LOG2E;
  }
  const float b_lo = bias_table[(2048 + 15) * NH + h] * LOG2E;
  const float b_hi = bias_table[(2048 + 31) * NH + h] * LOG2E;

  // Q fragments (pre-scaled in gemm epilogue); wave's rows = q0+qw*64+qt*16+l16
  const int qbase = q0 + qw * 64;
  half8_t qf[4][4];
  {
    const _Float16* tq = QRt + (size_t)(b * S_LEN + qbase + l16) * 1024 + h * 64 + quad * 8;
    const _Float16* pq = QRp + (size_t)(qbase + l16) * 1024 + h * 64 + quad * 8;
    #pragma unroll
    for (int qt = 0; qt < 4; ++qt)
      #pragma unroll
      for (int kf = 0; kf < 2; ++kf) {
        qf[kf][qt]     = *(const half8_t*)(tq + (size_t)qt * 16 * 1024 + kf * 32);
        qf[kf + 2][qt] = *(const half8_t*)(pq + (size_t)qt * 16 * 1024 + kf * 32);
      }
  }

  const _Float16* kgp = KG  + (size_t)bh * 131072;
  const _Float16* kpp = KGP + (size_t)h  * 131072;
  const _Float16* vgp = VG  + (size_t)bh * 131072;

  auto stage = [&](int t, int buf) {
    _Float16* dst = SK + buf * 12288;
    glds16(kgp + (size_t)t * 4096 + tid * 8, dst + tid * 8);
    glds16(kpp + (size_t)t * 4096 + tid * 8, dst + 4096 + tid * 8);
    glds16(vgp + (size_t)t * 4096 + tid * 8, dst + 8192 + tid * 8);
  };

  f32x4 oa[4][4] = {};
  float lpart[4] = {0.f, 0.f, 0.f, 0.f};
  union VP8 { half8_t h8; struct { half4_t lo, hi; } p; };

  auto tile_body = [&](int t, const _Float16* Bse) {
    const int dk = t * 64 - q0 - qw * 64;   // 64-granular
    const int f0 = kw * 2;

    // ---- all LDS reads up front (12x b128) ----
    half8_t kf0[4], kf1[4], vc[4];
    kf0[0] = *(const half8_t*)&Bse[f0 * 1024 + lane * 8];
    kf0[1] = *(const half8_t*)&Bse[f0 * 1024 + 512 + lane * 8];
    kf0[2] = *(const half8_t*)&Bse[4096 + f0 * 1024 + lane * 8];
    kf0[3] = *(const half8_t*)&Bse[4096 + f0 * 1024 + 512 + lane * 8];
    kf1[0] = *(const half8_t*)&Bse[(f0 + 1) * 1024 + lane * 8];
    kf1[1] = *(const half8_t*)&Bse[(f0 + 1) * 1024 + 512 + lane * 8];
    kf1[2] = *(const half8_t*)&Bse[4096 + (f0 + 1) * 1024 + lane * 8];
    kf1[3] = *(const half8_t*)&Bse[4096 + (f0 + 1) * 1024 + 512 + lane * 8];
    #pragma unroll
    for (int d = 0; d < 4; ++d)
      vc[d] = *(const half8_t*)&Bse[8192 + (kw * 4 + d) * 512 + lane * 8];

    // ---- bias init for both sub-tiles ----
    f32x4 s0[4], s1[4];
    if (dk < -128 || dk > 128) {
      float c = (dk < 0) ? b_lo : b_hi;
      #pragma unroll
      for (int qt = 0; qt < 4; ++qt) { s0[qt] = {c, c, c, c}; s1[qt] = {c, c, c, c}; }
    } else {
      #pragma unroll
      for (int qt = 0; qt < 4; ++qt) {
        int dbase = dk + f0 * 16 + quad * 4 - qt * 16 - l16 + 192;
        #pragma unroll
        for (int r = 0; r < 4; ++r) s0[qt][r] = biasl[dbase + r];
        #pragma unroll
        for (int r = 0; r < 4; ++r) s1[qt][r] = biasl[dbase + 16 + r];
      }
    }

    // ---- 32 QK MFMAs, one cluster ----
    __builtin_amdgcn_s_setprio(1);
    #pragma unroll
    for (int qt = 0; qt < 4; ++qt)
      #pragma unroll
      for (int kf = 0; kf < 4; ++kf)
        s0[qt] = mfma_qk(kf0[kf], qf[kf][qt], s0[qt]);
    #pragma unroll
    for (int qt = 0; qt < 4; ++qt)
      #pragma unroll
      for (int kf = 0; kf < 4; ++kf)
        s1[qt] = mfma_qk(kf1[kf], qf[kf][qt], s1[qt]);
    __builtin_amdgcn_s_setprio(0);

    // ---- exp both sub-tiles (same lpart fp order) ----
    VP8 pc[4];
    #pragma unroll
    for (int qt = 0; qt < 4; ++qt) {
      float p0 = fexp2(s0[qt][0]), p1 = fexp2(s0[qt][1]);
      float p2 = fexp2(s0[qt][2]), p3 = fexp2(s0[qt][3]);
      lpart[qt] += (p0 + p1) + (p2 + p3);
      union { half2_t h2[2]; half4_t h4; } u;
      u.h2[0] = __builtin_bit_cast(half2_t, __builtin_amdgcn_cvt_pkrtz(p0, p1));
      u.h2[1] = __builtin_bit_cast(half2_t, __builtin_amdgcn_cvt_pkrtz(p2, p3));
      pc[qt].p.lo = u.h4;
    }
    #pragma unroll
    for (int qt = 0; qt < 4; ++qt) {
      float p0 = fexp2(s1[qt][0]), p1 = fexp2(s1[qt][1]);
      float p2 = fexp2(s1[qt][2]), p3 = fexp2(s1[qt][3]);
      lpart[qt] += (p0 + p1) + (p2 + p3);
      union { half2_t h2[2]; half4_t h4; } u;
      u.h2[0] = __builtin_bit_cast(half2_t, __builtin_amdgcn_cvt_pkrtz(p0, p1));
      u.h2[1] = __builtin_bit_cast(half2_t, __builtin_amdgcn_cvt_pkrtz(p2, p3));
      pc[qt].p.hi = u.h4;
    }

    // ---- PV ----
    __builtin_amdgcn_s_setprio(1);
    #pragma unroll
    for (int d = 0; d < 4; ++d)
      #pragma unroll
      for (int qt = 0; qt < 4; ++qt)
        oa[d][qt] = mfma_qk(vc[d], pc[qt].h8, oa[d][qt]);
    __builtin_amdgcn_s_setprio(0);
  };

  stage(0, 0); stage(1, 1);
  __syncthreads();   // also covers biasl

  #pragma unroll 1
  for (int p = 0; p < 16; ++p) {
    const int base = (p & 1) * 2;          // compute buffers {base, base+1}
    if (p != 15) { stage(2 * p + 2, base ^ 2); stage(2 * p + 3, (base ^ 2) + 1); }
    tile_body(2 * p,     SK + base * 12288);
    tile_body(2 * p + 1, SK + (base + 1) * 12288);
    __syncthreads();   // pair p+1 landed; buffers {base,base+1} free
  }

  // ---- cross-half combine (kw=1 -> LDS, kw=0 adds + stores), 2 d-rounds ----
  #pragma unroll
  for (int qt = 0; qt < 4; ++qt) {
    lpart[qt] += __shfl_xor(lpart[qt], 16, 64);
    lpart[qt] += __shfl_xor(lpart[qt], 32, 64);
  }
  if (kw == 1) {
    if (quad == 0) {
      #pragma unroll
      for (int qt = 0; qt < 4; ++qt) lred[qw * 64 + qt * 16 + l16] = lpart[qt];
    }
    #pragma unroll
    for (int d = 0; d < 2; ++d)
      #pragma unroll
      for (int qt = 0; qt < 4; ++qt)
        *(f32x4*)&ored[(qw * 64 + qt * 16 + l16) * 36 + d * 16 + quad * 4] = oa[d][qt];
  }
  __syncthreads();
  float inv[4];
  if (kw == 0) {
    #pragma unroll
    for (int qt = 0; qt < 4; ++qt)
      inv[qt] = 1.f / (lpart[qt] + lred[qw * 64 + qt * 16 + l16]);
    #pragma unroll
    for (int d = 0; d < 2; ++d)
      #pragma unroll
      for (int qt = 0; qt < 4; ++qt) {
        f32x4 p = *(const f32x4*)&ored[(qw * 64 + qt * 16 + l16) * 36 + d * 16 + quad * 4];
        f32x4 sum = oa[d][qt] + p;
        sum[0] *= inv[qt]; sum[1] *= inv[qt]; sum[2] *= inv[qt]; sum[3] *= inv[qt];
        *(f32x4*)(out + (size_t)(b * S_LEN + qbase + qt * 16 + l16) * 1024 +
                  h * 64 + d * 16 + quad * 4) = sum;
      }
  }
  __syncthreads();
  if (kw == 1) {
    #pragma unroll
    for (int d = 2; d < 4; ++d)
      #pragma unroll
      for (int qt = 0; qt < 4; ++qt)
        *(f32x4*)&ored[(qw * 64 + qt * 16 + l16) * 36 + (d - 2) * 16 + quad * 4] = oa[d][qt];
  }
  __syncthreads();
  if (kw == 0) {
    #pragma unroll
    for (int d = 2; d < 4; ++d)
      #pragma unroll
      for (int qt = 0; qt < 4; ++qt) {
        f32x4 p = *(const f32x4*)&ored[(qw * 64 + qt * 16 + l16) * 36 + (d - 2) * 16 + quad * 4];
        f32x4 sum = oa[d][qt] + p;
        sum[0] *= inv[qt]; sum[1] *= inv[qt]; sum[2] *= inv[qt]; sum[3] *= inv[qt];
        *(f32x4*)(out + (size_t)(b * S_LEN + qbase + qt * 16 + l16) * 1024 +
                  h * 64 + (d - 2) * 16 + quad * 4 + 32) = sum;
      }
  }
}

extern "C" void kernel_launch(void* const* d_in, const int* in_sizes, int n_in,
                              void* d_out, int out_size, void* d_ws, size_t ws_size,
                              hipStream_t stream) {
  (void)in_sizes; (void)n_in; (void)out_size; (void)ws_size;
  const float* x          = (const float*)d_in[0];
  const float* pos_embed  = (const float*)d_in[1];
  const float* W_pos_kq   = (const float*)d_in[2];
  const float* W_tok_kqv  = (const float*)d_in[3];
  const float* bias_table = (const float*)d_in[4];
  float* out = (float*)d_out;

  _Float16* ws = (_Float16*)d_ws;
  _Float16* pos_f  = ws;                     // 2,097,152
  _Float16* wt_pos = ws + 2097152;           // 2,097,152
  _Float16* x_f    = ws + 4194304;           // 4,194,304
  _Float16* wt_tok = ws + 8388608;           // 3,145,728
  _Float16* KG     = ws + 11534336;          // 4,194,304
  _Float16* KGP    = ws + 15728640;          // 2,097,152
  _Float16* VG     = ws + 17825792;          // 4,194,304
  _Float16* QRt    = ws + 22020096;          // 4,194,304
  _Float16* QRp    = ws + 26214400;          // 2,097,152
  // total 28,311,552 halfs = 56.6 MB

  const float QSCALE = 0.08838834764831845f * LOG2E;  // 1/sqrt(2*64) * log2e

  prep_kernel<<<4352, 256, 0, stream>>>(x, pos_embed, W_pos_kq, W_tok_kqv,
                                        x_f, pos_f, wt_pos, wt_tok);
  gemm_all_kernel<<<512, 512, 0, stream>>>(pos_f, wt_pos, x_f, wt_tok,
                                           KGP, QRp, KG, QRt, VG, QSCALE);
  flash_kernel<<<256, 512, 0, stream>>>(QRt, QRp, KG, KGP, VG, bias_table, out);
}